// Round 5
// baseline (1039.340 us; speedup 1.0000x reference)
//
#include <hip/hip_runtime.h>
#include <stdint.h>
#include <math.h>

#define NOISE_LEVEL 0.02f
#define CROSSTALK   0.05f
#define COHERENCE   0.03f

typedef __attribute__((ext_vector_type(8))) short short8;
typedef __attribute__((ext_vector_type(4))) float f32x4;

#define TF_ROUND(x0,x1,R) { x0 += x1; x1 = ((x1 << (R)) | (x1 >> (32-(R)))); x1 ^= x0; }

__host__ __device__ inline void threefry2x32(uint32_t k0, uint32_t k1,
                                             uint32_t x0, uint32_t x1,
                                             uint32_t& o0, uint32_t& o1)
{
  uint32_t ks2 = k0 ^ k1 ^ 0x1BD11BDAu;
  x0 += k0; x1 += k1;
  TF_ROUND(x0,x1,13) TF_ROUND(x0,x1,15) TF_ROUND(x0,x1,26) TF_ROUND(x0,x1,6)
  x0 += k1; x1 += ks2 + 1u;
  TF_ROUND(x0,x1,17) TF_ROUND(x0,x1,29) TF_ROUND(x0,x1,16) TF_ROUND(x0,x1,24)
  x0 += ks2; x1 += k0 + 2u;
  TF_ROUND(x0,x1,13) TF_ROUND(x0,x1,15) TF_ROUND(x0,x1,26) TF_ROUND(x0,x1,6)
  x0 += k0; x1 += k1 + 3u;
  TF_ROUND(x0,x1,17) TF_ROUND(x0,x1,29) TF_ROUND(x0,x1,16) TF_ROUND(x0,x1,24)
  x0 += k1; x1 += ks2 + 4u;
  TF_ROUND(x0,x1,13) TF_ROUND(x0,x1,15) TF_ROUND(x0,x1,26) TF_ROUND(x0,x1,6)
  o0 = x0 + ks2; o1 = x1 + k0 + 5u;
}

// threefry_partitionable bits for 32-bit draws: XOR of the two output words.
__device__ inline uint32_t jax_bits(uint32_t k0, uint32_t k1, uint32_t idx)
{
  uint32_t o0, o1; threefry2x32(k0, k1, 0u, idx, o0, o1); return o0 ^ o1;
}

// JAX random.normal(float32): u ~ uniform[-0.99999994, 1); n = sqrt(2)*erfinv(u)
__device__ inline float jax_normal(uint32_t k0, uint32_t k1, uint32_t idx)
{
  uint32_t bits = jax_bits(k0, k1, idx);
  float f = __uint_as_float((bits >> 9) | 0x3f800000u) - 1.0f;   // [0,1)
  float u = fmaf(f, 2.0f, -0.99999994f);
  u = fmaxf(-0.99999994f, u);
  float w = -__logf(fmaf(-u, u, 1.0f));
  float p;
  if (w < 5.0f) {
    w -= 2.5f;
    p = 2.81022636e-08f;
    p = fmaf(p, w, 3.43273939e-07f);
    p = fmaf(p, w, -3.5233877e-06f);
    p = fmaf(p, w, -4.39150654e-06f);
    p = fmaf(p, w, 0.00021858087f);
    p = fmaf(p, w, -0.00125372503f);
    p = fmaf(p, w, -0.00417768164f);
    p = fmaf(p, w, 0.246640727f);
    p = fmaf(p, w, 1.50140941f);
  } else {
    w = sqrtf(w) - 3.0f;
    p = -0.000200214257f;
    p = fmaf(p, w, 0.000100950558f);
    p = fmaf(p, w, 0.00134934322f);
    p = fmaf(p, w, -0.00367342844f);
    p = fmaf(p, w, 0.00573950773f);
    p = fmaf(p, w, -0.0076224613f);
    p = fmaf(p, w, 0.00943887047f);
    p = fmaf(p, w, 1.00167406f);
    p = fmaf(p, w, 2.83297682f);
  }
  return 1.41421354f * (p * u);
}

__device__ inline float cos_small(float p)
{
  float p2 = p * p;
  return 1.0f + p2 * (-0.5f + p2 * (4.16666679e-02f + p2 * (-1.38888892e-03f)));
}

// exact-algebra tanh via fast exp: tanh(x) = sign(x) * (1 - 2/(e^{2|x|}+1)).
// abs err <= ~1.2e-7 (cancellation-limited near 0); inf-safe for large |x|.
__device__ inline float tanh_fast(float x)
{
  float ax = fabsf(x);
  float e = __expf(2.0f * ax);
  float r = 1.0f - 2.0f / (e + 1.0f);
  return copysignf(r, x);
}

// round-to-nearest-even fp32 -> bf16, and back
__device__ inline unsigned short bf16_rn(float x)
{
  uint32_t u = __float_as_uint(x);
  uint32_t r = u + 0x7FFFu + ((u >> 16) & 1u);
  return (unsigned short)(r >> 16);
}
__device__ inline float bf16_f(unsigned short h)
{
  return __uint_as_float(((uint32_t)h) << 16);
}

// ---------------------------------------------------------------------------
// split_pass: hi/lo bf16 planes of in (optionally tanh first).
// ---------------------------------------------------------------------------
__global__ __launch_bounds__(256)
void split_pass(const float* __restrict__ in, unsigned short* __restrict__ hi,
                unsigned short* __restrict__ lo, int n4, int do_tanh)
{
  int g = blockIdx.x * 256 + threadIdx.x;
  const int stride = gridDim.x * 256;
  for (; g < n4; g += stride) {
    float4 v = *(const float4*)&in[(size_t)g * 4];
    if (do_tanh) {
      v.x = tanh_fast(v.x); v.y = tanh_fast(v.y);
      v.z = tanh_fast(v.z); v.w = tanh_fast(v.w);
    }
    float xs[4] = {v.x, v.y, v.z, v.w};
    ushort4 h, l;
    unsigned short* hp = &h.x; unsigned short* lp = &l.x;
    #pragma unroll
    for (int e = 0; e < 4; ++e) {
      hp[e] = bf16_rn(xs[e]);
      lp[e] = bf16_rn(xs[e] - bf16_f(hp[e]));
    }
    *(ushort4*)&hi[(size_t)g * 4] = h;
    *(ushort4*)&lo[(size_t)g * 4] = l;
  }
}

// ---------------------------------------------------------------------------
// Pure-bf16 4-plane MFMA GEMM (fp32 via Ah*Bh + Ah*Bl + Al*Bh):
//   out = tanh(A @ W^T + bias) + 0.02*normal(key, r*N+c); colabs += sum|v|.
// 128x128 tile, BK=32, 4 waves, double-buffered LDS (2-phase counted pipeline).
// LDS logical layout per plane: [kg(4)][row(128)][8 bf16] - fragment-major, so
// fragment ds_read_b128 is 16 lanes x 256B contiguous per lg group = even
// bank load (conflict-free). Achieved by permuting the per-lane GLOBAL source
// of global_load_lds while keeping the LDS destination linear (m173 pattern).
// Grid: bn-major + bijective XCD swizzle (A-panel streamed once).
// ---------------------------------------------------------------------------
#define BM 128
#define BN 128
#define BK 32
#define PLANESH 4096          // ushorts per plane tile (128*32)
#define BUFSH   (4 * PLANESH) // ushorts per buffer (4 planes)

__global__ __launch_bounds__(256)
void gemm_mfma(const unsigned short* __restrict__ Agh, const unsigned short* __restrict__ Agl,
               const unsigned short* __restrict__ Bgh, const unsigned short* __restrict__ Bgl,
               const float* __restrict__ bias, float* __restrict__ out,
               float* __restrict__ colabs, int M, int N, int K,
               uint32_t nk0, uint32_t nk1)
{
  __shared__ __align__(16) unsigned short lds[2 * BUFSH];   // 64 KiB

  const int t = threadIdx.x;
  // bijective XCD swizzle (gridDim.x % 8 == 0), then bn-major decode
  const int nwg = gridDim.x;
  const int wg = (blockIdx.x & 7) * (nwg >> 3) + (blockIdx.x >> 3);
  const int nbn = N / BN;
  const int bn = wg & (nbn - 1);
  const int bm = wg / nbn;
  const int blockM = bm * BM, blockN = bn * BN;

  const int lane = t & 63;
  const int w = t >> 6;
  const int wr = w >> 1, wc = w & 1;
  const int lm = lane & 15, lg = lane >> 4;

  // staging: wave w owns one plane (0=Ah,1=Al,2=Bh,3=Bl)
  const unsigned short* gplane;
  int grow0;
  if (w == 0)      { gplane = Agh; grow0 = blockM; }
  else if (w == 1) { gplane = Agl; grow0 = blockM; }
  else if (w == 2) { gplane = Bgh; grow0 = blockN; }
  else             { gplane = Bgl; grow0 = blockN; }
  // inst i, lane l: LDS plane-offset (i*64+l)*8 ushorts; content must be
  // plane[row = (i&1)*64 + l][kt*BK + (i>>1)*8 .. +7]
  const unsigned short* gsrc0 = gplane + (size_t)(grow0 + lane) * K;
  const unsigned short* gsrc1 = gplane + (size_t)(grow0 + 64 + lane) * K;
  unsigned short* lplane = lds + w * PLANESH;

#define STAGE(buf, kt_) {                                                      \
    unsigned short* lp = lplane + (buf) * BUFSH;                               \
    const unsigned short* s0 = gsrc0 + (kt_) * BK;                             \
    const unsigned short* s1 = gsrc1 + (kt_) * BK;                             \
    _Pragma("unroll")                                                          \
    for (int i = 0; i < 8; ++i) {                                              \
      const unsigned short* s = ((i & 1) ? s1 : s0) + (i >> 1) * 8;            \
      __builtin_amdgcn_global_load_lds((const void*)s, (void*)(lp + i * 512),  \
                                       16, 0, 0);                              \
    } }

  f32x4 acc[4][4];
  #pragma unroll
  for (int i = 0; i < 4; ++i)
    #pragma unroll
    for (int j = 0; j < 4; ++j) acc[i][j] = 0.0f;

  const int nk = K / BK;
  STAGE(0, 0);
  __syncthreads();                    // vmcnt(0)+barrier: buf0 ready
  int cur = 0;

  for (int kt = 0; kt < nk; ++kt) {
    if (kt + 1 < nk) STAGE(cur ^ 1, kt + 1);   // prefetch overlaps compute

    const unsigned short* base = lds + cur * BUFSH;
    short8 fah[4], fal[4], fbh[4], fbl[4];
    #pragma unroll
    for (int fm = 0; fm < 4; ++fm) {
      int ro = (wr * 64 + fm * 16 + lm) * 8 + lg * 1024;
      fah[fm] = *(const short8*)(base + 0 * PLANESH + ro);
      fal[fm] = *(const short8*)(base + 1 * PLANESH + ro);
    }
    #pragma unroll
    for (int fn = 0; fn < 4; ++fn) {
      int ro = (wc * 64 + fn * 16 + lm) * 8 + lg * 1024;
      fbh[fn] = *(const short8*)(base + 2 * PLANESH + ro);
      fbl[fn] = *(const short8*)(base + 3 * PLANESH + ro);
    }
    #pragma unroll
    for (int fm = 0; fm < 4; ++fm)
      #pragma unroll
      for (int fn = 0; fn < 4; ++fn) {
        acc[fm][fn] = __builtin_amdgcn_mfma_f32_16x16x32_bf16(fah[fm], fbh[fn], acc[fm][fn], 0, 0, 0);
        acc[fm][fn] = __builtin_amdgcn_mfma_f32_16x16x32_bf16(fah[fm], fbl[fn], acc[fm][fn], 0, 0, 0);
        acc[fm][fn] = __builtin_amdgcn_mfma_f32_16x16x32_bf16(fal[fm], fbh[fn], acc[fm][fn], 0, 0, 0);
      }

    __syncthreads();                  // drains prefetch loads; cur reads done
    cur ^= 1;
  }

  // epilogue: C layout col=lane&15, row=(lane>>4)*4+reg  [m89-verified]
  #pragma unroll
  for (int fn = 0; fn < 4; ++fn) {
    int gc = blockN + wc * 64 + fn * 16 + lm;
    float bv = bias[gc];
    float cp = 0.0f;
    #pragma unroll
    for (int fm = 0; fm < 4; ++fm) {
      int gr0 = blockM + wr * 64 + fm * 16 + lg * 4;
      #pragma unroll
      for (int j = 0; j < 4; ++j) {
        int gr = gr0 + j;
        float nrm = jax_normal(nk0, nk1, (uint32_t)(gr * N + gc));
        float v = tanh_fast(acc[fm][fn][j] + bv) + NOISE_LEVEL * nrm;
        out[(size_t)gr * N + gc] = v;
        cp += fabsf(v);
      }
    }
    cp += __shfl_xor(cp, 16);
    cp += __shfl_xor(cp, 32);
    if (lg == 0) atomicAdd(&colabs[gc], cp);
  }
#undef STAGE
}

// ---------------------------------------------------------------------------
// thermal = 0.7*prev + 0.3*(colabs*CROSSTALK); tn[i] = CROSSTALK * sum thermal[j]/(i-j)^2
// ---------------------------------------------------------------------------
__global__ __launch_bounds__(256)
void thermal_tn(const float* __restrict__ colabs, const float* __restrict__ prev_thermal,
                float* __restrict__ thermal_out, float* __restrict__ tn_out, int has_prev)
{
  __shared__ float th[2048];
  __shared__ float inv[2048];
  const int t = threadIdx.x;
  for (int j = t; j < 2048; j += 256) {
    float lt = colabs[j] * CROSSTALK;
    float pv = has_prev ? prev_thermal[j] : 0.0f;
    th[j] = 0.7f * pv + 0.3f * lt;
    float d = (float)j;
    inv[j] = (j == 0) ? 0.0f : 1.0f / (d * d);
  }
  __syncthreads();
  const int i = blockIdx.x * 256 + t;
  float s = 0.0f;
  #pragma unroll 4
  for (int j = 0; j < 2048; ++j) {
    int d = i - j; d = d < 0 ? -d : d;
    s += th[j] * inv[d];
  }
  tn_out[i] = s * CROSSTALK;
  thermal_out[i] = th[i];
}

// ---------------------------------------------------------------------------
// coherence + split: v = (x + tn) with phase interference, written as bf16
// hi/lo planes (GEMM2's A operand).
// ---------------------------------------------------------------------------
__global__ __launch_bounds__(256)
void coherence_split(const float* __restrict__ x, const float* __restrict__ tn,
                     unsigned short* __restrict__ hi, unsigned short* __restrict__ lo,
                     uint32_t pk0, uint32_t pk1, int total4)
{
  int g = blockIdx.x * blockDim.x + threadIdx.x;
  const int stride = gridDim.x * blockDim.x;
  for (; g < total4; g += stride) {
    size_t base = (size_t)g * 4;
    float4 v = *(const float4*)&x[base];
    int col = (int)(base & 2047);
    const float4 tv = *(const float4*)&tn[col];
    float vv[4] = {v.x + tv.x, v.y + tv.y, v.z + tv.z, v.w + tv.w};
    ushort4 h, l;
    unsigned short* hp = &h.x; unsigned short* lp = &l.x;
    #pragma unroll
    for (int e = 0; e < 4; ++e) {
      float ph = COHERENCE * jax_normal(pk0, pk1, (uint32_t)base + e);
      float cp = cos_small(ph);
      float xv = vv[e] + (vv[e] * cp - vv[e]) * COHERENCE;
      hp[e] = bf16_rn(xv);
      lp[e] = bf16_rn(xv - bf16_f(hp[e]));
    }
    *(ushort4*)&hi[base] = h;
    *(ushort4*)&lo[base] = l;
  }
}

// ---------------------------------------------------------------------------
// Final: x2 = (a2 + tn2) with coherence; out[b,:] = x2[b,:] @ Wout^T + bout
// ---------------------------------------------------------------------------
__global__ __launch_bounds__(256)
void final_out(const float* __restrict__ a2, const float* __restrict__ tn2,
               const float* __restrict__ Wout, const float* __restrict__ bout,
               float* __restrict__ out, uint32_t pk0, uint32_t pk1)
{
  const int wave = threadIdx.x >> 6;
  const int lane = threadIdx.x & 63;
  const int b = blockIdx.x * 4 + wave;
  const float* row = a2 + (size_t)b * 2048;
  float acc0 = 0.0f, acc1 = 0.0f;
  #pragma unroll
  for (int i = 0; i < 8; ++i) {
    int h = lane * 4 + i * 256;
    float4 v  = *(const float4*)&row[h];
    float4 tv = *(const float4*)&tn2[h];
    float4 w0 = *(const float4*)&Wout[h];
    float4 w1 = *(const float4*)&Wout[2048 + h];
    float xs[4]  = {v.x + tv.x, v.y + tv.y, v.z + tv.z, v.w + tv.w};
    float w0s[4] = {w0.x, w0.y, w0.z, w0.w};
    float w1s[4] = {w1.x, w1.y, w1.z, w1.w};
    uint32_t fb = (uint32_t)(b * 2048 + h);
    #pragma unroll
    for (int e = 0; e < 4; ++e) {
      float ph = COHERENCE * jax_normal(pk0, pk1, fb + e);
      float cp = cos_small(ph);
      float xv = xs[e] + (xs[e] * cp - xs[e]) * COHERENCE;
      acc0 = fmaf(xv, w0s[e], acc0);
      acc1 = fmaf(xv, w1s[e], acc1);
    }
  }
  #pragma unroll
  for (int off = 32; off > 0; off >>= 1) {
    acc0 += __shfl_down(acc0, off);
    acc1 += __shfl_down(acc1, off);
  }
  if (lane == 0) {
    out[(size_t)b * 2 + 0] = acc0 + bout[0];
    out[(size_t)b * 2 + 1] = acc1 + bout[1];
  }
}

extern "C" void kernel_launch(void* const* d_in, const int* in_sizes, int n_in,
                              void* d_out, int out_size, void* d_ws, size_t ws_size,
                              hipStream_t stream)
{
  (void)in_sizes; (void)n_in; (void)out_size; (void)ws_size;
  const float* x    = (const float*)d_in[0];
  const float* W1   = (const float*)d_in[1];
  const float* b1   = (const float*)d_in[2];
  const float* W2   = (const float*)d_in[3];
  const float* b2   = (const float*)d_in[4];
  const float* Wout = (const float*)d_in[5];
  const float* bout = (const float*)d_in[6];
  float* out = (float*)d_out;

  const int M = 8192, H = 2048, Din = 1024;
  const size_t MB64 = (size_t)64 * 1024 * 1024;

  char* ws = (char*)d_ws;
  // P0 [0,64MB): a1 fp32 (GEMM1 out), later reused as a2 fp32 (GEMM2 out)
  float* a_f32 = (float*)ws;
  // P1 [64MB,128MB): first xth/xtl (GEMM1 A planes), then a1h/a1l
  unsigned short* p1  = (unsigned short*)(ws + MB64);
  unsigned short* xth = p1;
  unsigned short* xtl = p1 + (size_t)M * Din;
  unsigned short* a1h = p1;
  unsigned short* a1l = p1 + (size_t)M * H;
  // P2 [128MB,152MB): W planes
  unsigned short* wp  = (unsigned short*)(ws + 2 * MB64);
  unsigned short* W1h = wp;
  unsigned short* W1l = wp + (size_t)H * Din;
  unsigned short* W2h = wp + (size_t)2 * H * Din;
  unsigned short* W2l = wp + (size_t)2 * H * Din + (size_t)H * H;
  // small arrays
  float* small = (float*)(ws + 2 * MB64 + (size_t)24 * 1024 * 1024);
  float* colabs1  = small + 0 * H;
  float* colabs2  = small + 1 * H;
  float* thermal1 = small + 2 * H;
  float* thermal2 = small + 3 * H;
  float* tn1      = small + 4 * H;
  float* tn2      = small + 5 * H;

  // fold_in keys: key(42) = (0,42); fold_in(key, d) = threefry(key, [0,d])
  uint32_t kn0a, kn0b, kp0a, kp0b, kn1a, kn1b, kp1a, kp1b;
  threefry2x32(0u, 42u, 0u, 0u, kn0a, kn0b);   // noise, layer 0
  threefry2x32(0u, 42u, 0u, 1u, kp0a, kp0b);   // phase, layer 0
  threefry2x32(0u, 42u, 0u, 2u, kn1a, kn1b);   // noise, layer 1
  threefry2x32(0u, 42u, 0u, 3u, kp1a, kp1b);   // phase, layer 1

  hipMemsetAsync(colabs1, 0, 2 * H * sizeof(float), stream);

  // pre-split passes
  split_pass<<<2048, 256, 0, stream>>>(W1, W1h, W1l, H * Din / 4, 0);
  split_pass<<<2048, 256, 0, stream>>>(W2, W2h, W2l, H * H / 4, 0);
  split_pass<<<2048, 256, 0, stream>>>(x, xth, xtl, M * Din / 4, 1);

  const int nblk = (M / BM) * (H / BN);   // 64*16 = 1024 (multiple of 8)
  gemm_mfma<<<nblk, 256, 0, stream>>>(xth, xtl, W1h, W1l, b1, a_f32, colabs1,
                                      M, H, Din, kn0a, kn0b);
  thermal_tn<<<H / 256, 256, 0, stream>>>(colabs1, nullptr, thermal1, tn1, 0);
  coherence_split<<<2048, 256, 0, stream>>>(a_f32, tn1, a1h, a1l, kp0a, kp0b, M * H / 4);
  gemm_mfma<<<nblk, 256, 0, stream>>>(a1h, a1l, W2h, W2l, b2, a_f32, colabs2,
                                      M, H, H, kn1a, kn1b);
  thermal_tn<<<H / 256, 256, 0, stream>>>(colabs2, thermal1, thermal2, tn2, 1);
  final_out<<<M / 4, 256, 0, stream>>>(a_f32, tn2, Wout, bout, out, kp1a, kp1b);
}

// Round 6
// 567.663 us; speedup vs baseline: 1.8309x; 1.8309x over previous
//
#include <hip/hip_runtime.h>
#include <stdint.h>
#include <math.h>

#define NOISE_LEVEL 0.02f
#define CROSSTALK   0.05f
#define COHERENCE   0.03f

typedef __attribute__((ext_vector_type(8))) short short8;
typedef __attribute__((ext_vector_type(4))) float f32x4;

#define TF_ROUND(x0,x1,R) { x0 += x1; x1 = ((x1 << (R)) | (x1 >> (32-(R)))); x1 ^= x0; }

__host__ __device__ inline void threefry2x32(uint32_t k0, uint32_t k1,
                                             uint32_t x0, uint32_t x1,
                                             uint32_t& o0, uint32_t& o1)
{
  uint32_t ks2 = k0 ^ k1 ^ 0x1BD11BDAu;
  x0 += k0; x1 += k1;
  TF_ROUND(x0,x1,13) TF_ROUND(x0,x1,15) TF_ROUND(x0,x1,26) TF_ROUND(x0,x1,6)
  x0 += k1; x1 += ks2 + 1u;
  TF_ROUND(x0,x1,17) TF_ROUND(x0,x1,29) TF_ROUND(x0,x1,16) TF_ROUND(x0,x1,24)
  x0 += ks2; x1 += k0 + 2u;
  TF_ROUND(x0,x1,13) TF_ROUND(x0,x1,15) TF_ROUND(x0,x1,26) TF_ROUND(x0,x1,6)
  x0 += k0; x1 += k1 + 3u;
  TF_ROUND(x0,x1,17) TF_ROUND(x0,x1,29) TF_ROUND(x0,x1,16) TF_ROUND(x0,x1,24)
  x0 += k1; x1 += ks2 + 4u;
  TF_ROUND(x0,x1,13) TF_ROUND(x0,x1,15) TF_ROUND(x0,x1,26) TF_ROUND(x0,x1,6)
  o0 = x0 + ks2; o1 = x1 + k0 + 5u;
}

// threefry_partitionable bits for 32-bit draws: XOR of the two output words.
__device__ inline uint32_t jax_bits(uint32_t k0, uint32_t k1, uint32_t idx)
{
  uint32_t o0, o1; threefry2x32(k0, k1, 0u, idx, o0, o1); return o0 ^ o1;
}

// JAX random.normal(float32): u ~ uniform[-0.99999994, 1); n = sqrt(2)*erfinv(u)
__device__ inline float jax_normal(uint32_t k0, uint32_t k1, uint32_t idx)
{
  uint32_t bits = jax_bits(k0, k1, idx);
  float f = __uint_as_float((bits >> 9) | 0x3f800000u) - 1.0f;   // [0,1)
  float u = fmaf(f, 2.0f, -0.99999994f);
  u = fmaxf(-0.99999994f, u);
  float w = -__logf(fmaf(-u, u, 1.0f));
  float p;
  if (w < 5.0f) {
    w -= 2.5f;
    p = 2.81022636e-08f;
    p = fmaf(p, w, 3.43273939e-07f);
    p = fmaf(p, w, -3.5233877e-06f);
    p = fmaf(p, w, -4.39150654e-06f);
    p = fmaf(p, w, 0.00021858087f);
    p = fmaf(p, w, -0.00125372503f);
    p = fmaf(p, w, -0.00417768164f);
    p = fmaf(p, w, 0.246640727f);
    p = fmaf(p, w, 1.50140941f);
  } else {
    w = sqrtf(w) - 3.0f;
    p = -0.000200214257f;
    p = fmaf(p, w, 0.000100950558f);
    p = fmaf(p, w, 0.00134934322f);
    p = fmaf(p, w, -0.00367342844f);
    p = fmaf(p, w, 0.00573950773f);
    p = fmaf(p, w, -0.0076224613f);
    p = fmaf(p, w, 0.00943887047f);
    p = fmaf(p, w, 1.00167406f);
    p = fmaf(p, w, 2.83297682f);
  }
  return 1.41421354f * (p * u);
}

__device__ inline float cos_small(float p)
{
  float p2 = p * p;
  return 1.0f + p2 * (-0.5f + p2 * (4.16666679e-02f + p2 * (-1.38888892e-03f)));
}

// exact-algebra tanh via fast exp; abs err <= ~1.2e-7, inf-safe.
__device__ inline float tanh_fast(float x)
{
  float ax = fabsf(x);
  float e = __expf(2.0f * ax);
  float r = 1.0f - 2.0f / (e + 1.0f);
  return copysignf(r, x);
}

// round-to-nearest-even fp32 -> bf16, and back
__device__ inline unsigned short bf16_rn(float x)
{
  uint32_t u = __float_as_uint(x);
  uint32_t r = u + 0x7FFFu + ((u >> 16) & 1u);
  return (unsigned short)(r >> 16);
}
__device__ inline float bf16_f(unsigned short h)
{
  return __uint_as_float(((uint32_t)h) << 16);
}

// ---------------------------------------------------------------------------
// Packed-plane layout (shared by packers and GEMM):
//   plane tile (rb, kt) occupies ushorts [(rb*Kt + kt)*4096, +4096)
//   within tile: [kg(4)][row(128)][8]  (kg = k-quarter of BK=32, 8 bf16 each)
// Linear output slot for thread g (8 elems): offset = g*8, with
//   tile = g>>9, s = g&511, kg = s>>7, row = s&127  -> writes fully coalesced.
// ---------------------------------------------------------------------------

// split_pack: fp32 [R][K] -> packed hi/lo bf16 planes (optional tanh first).
__global__ __launch_bounds__(256)
void split_pack(const float* __restrict__ in, unsigned short* __restrict__ hi,
                unsigned short* __restrict__ lo, int R, int K, int kshift,
                int do_tanh)
{
  const int nslots = R * (K >> 3);
  const int ktm = (K >> 5) - 1;
  int g = blockIdx.x * 256 + threadIdx.x;
  const int stride = gridDim.x * 256;
  for (; g < nslots; g += stride) {
    int tile = g >> 9;
    int s = g & 511;
    int kg = s >> 7, row = s & 127;
    int rb = tile >> kshift, kt = tile & ktm;
    int r = rb * 128 + row;
    int k = kt * 32 + kg * 8;
    const float* src = in + (size_t)r * K + k;
    float4 v0 = *(const float4*)src;
    float4 v1 = *(const float4*)(src + 4);
    float xs[8] = {v0.x, v0.y, v0.z, v0.w, v1.x, v1.y, v1.z, v1.w};
    unsigned short hv[8], lv[8];
    #pragma unroll
    for (int e = 0; e < 8; ++e) {
      float x = do_tanh ? tanh_fast(xs[e]) : xs[e];
      hv[e] = bf16_rn(x);
      lv[e] = bf16_rn(x - bf16_f(hv[e]));
    }
    *(short8*)&hi[(size_t)g * 8] = *(short8*)hv;
    *(short8*)&lo[(size_t)g * 8] = *(short8*)lv;
  }
}

// coherence + split + pack: v = (x + tn) with phase interference -> packed planes.
__global__ __launch_bounds__(256)
void coherence_split_pack(const float* __restrict__ x, const float* __restrict__ tn,
                          unsigned short* __restrict__ hi, unsigned short* __restrict__ lo,
                          uint32_t pk0, uint32_t pk1, int R, int K, int kshift)
{
  const int nslots = R * (K >> 3);
  const int ktm = (K >> 5) - 1;
  int g = blockIdx.x * 256 + threadIdx.x;
  const int stride = gridDim.x * 256;
  for (; g < nslots; g += stride) {
    int tile = g >> 9;
    int s = g & 511;
    int kg = s >> 7, row = s & 127;
    int rb = tile >> kshift, kt = tile & ktm;
    int r = rb * 128 + row;
    int k = kt * 32 + kg * 8;
    const float* src = x + (size_t)r * K + k;
    float4 v0 = *(const float4*)src;
    float4 v1 = *(const float4*)(src + 4);
    float4 t0 = *(const float4*)&tn[k];
    float4 t1 = *(const float4*)&tn[k + 4];
    float vv[8] = {v0.x + t0.x, v0.y + t0.y, v0.z + t0.z, v0.w + t0.w,
                   v1.x + t1.x, v1.y + t1.y, v1.z + t1.z, v1.w + t1.w};
    uint32_t fb = (uint32_t)(r * K + k);
    unsigned short hv[8], lv[8];
    #pragma unroll
    for (int e = 0; e < 8; ++e) {
      float ph = COHERENCE * jax_normal(pk0, pk1, fb + e);
      float cp = cos_small(ph);
      float xv = vv[e] + (vv[e] * cp - vv[e]) * COHERENCE;
      hv[e] = bf16_rn(xv);
      lv[e] = bf16_rn(xv - bf16_f(hv[e]));
    }
    *(short8*)&hi[(size_t)g * 8] = *(short8*)hv;
    *(short8*)&lo[(size_t)g * 8] = *(short8*)lv;
  }
}

// ---------------------------------------------------------------------------
// Pure-bf16 4-plane MFMA GEMM on packed planes (fp32 via Ah*Bh+Ah*Bl+Al*Bh):
//   out = tanh(A @ W^T + bias) + 0.02*normal(key, r*N+c); colabs += sum|v|.
// 128x128 tile, BK=32, 4 waves, double-buffered; staging = straight
// contiguous copy of one 8KB plane tile per wave (8 x global_load_lds 1KB,
// fully coalesced, linear LDS dest). Fragment ds_read_b128 conflict-free.
// Grid: bn-minor decode + bijective XCD swizzle (nwg % 8 == 0).
// ---------------------------------------------------------------------------
#define BM 128
#define BN 128
#define BK 32
#define PLANESH 4096          // ushorts per plane tile (128*32)
#define BUFSH   (4 * PLANESH) // ushorts per buffer (4 planes)

__global__ __launch_bounds__(256)
void gemm_mfma(const unsigned short* __restrict__ Agh, const unsigned short* __restrict__ Agl,
               const unsigned short* __restrict__ Bgh, const unsigned short* __restrict__ Bgl,
               const float* __restrict__ bias, float* __restrict__ out,
               float* __restrict__ colabs, int M, int N, int K,
               uint32_t nk0, uint32_t nk1)
{
  __shared__ __align__(16) unsigned short lds[2 * BUFSH];   // 64 KiB

  const int t = threadIdx.x;
  const int nwg = gridDim.x;
  const int wg = (blockIdx.x & 7) * (nwg >> 3) + (blockIdx.x >> 3);
  const int nbn = N / BN;
  const int bn = wg & (nbn - 1);       // bn-minor: 16 consecutive wgs share A panel
  const int bm = wg / nbn;
  const int blockM = bm * BM, blockN = bn * BN;

  const int lane = t & 63;
  const int w = t >> 6;
  const int wr = w >> 1, wc = w & 1;
  const int lm = lane & 15, lg = lane >> 4;

  // staging: wave w owns one plane (0=Ah,1=Al,2=Bh,3=Bl); tiles are contiguous
  const unsigned short* gplane;
  int blk;
  if (w == 0)      { gplane = Agh; blk = bm; }
  else if (w == 1) { gplane = Agl; blk = bm; }
  else if (w == 2) { gplane = Bgh; blk = bn; }
  else             { gplane = Bgl; blk = bn; }
  const int ktiles = K >> 5;
  const unsigned short* gtile0 = gplane + ((size_t)blk * ktiles) * PLANESH + lane * 8;
  unsigned short* lplane = lds + w * PLANESH;

#define STAGE(buf, kt_) {                                                      \
    unsigned short* lp = lplane + (buf) * BUFSH;                               \
    const unsigned short* s = gtile0 + (size_t)(kt_) * PLANESH;                \
    _Pragma("unroll")                                                          \
    for (int i = 0; i < 8; ++i)                                                \
      __builtin_amdgcn_global_load_lds((const void*)(s + i * 512),             \
                                       (void*)(lp + i * 512), 16, 0, 0);       \
  }

  f32x4 acc[4][4];
  #pragma unroll
  for (int i = 0; i < 4; ++i)
    #pragma unroll
    for (int j = 0; j < 4; ++j) acc[i][j] = 0.0f;

  const int nk = ktiles;
  STAGE(0, 0);
  __syncthreads();                    // vmcnt(0)+barrier: buf0 ready
  int cur = 0;

  for (int kt = 0; kt < nk; ++kt) {
    if (kt + 1 < nk) STAGE(cur ^ 1, kt + 1);   // prefetch overlaps compute

    const unsigned short* base = lds + cur * BUFSH;
    short8 fah[4], fal[4], fbh[4], fbl[4];
    #pragma unroll
    for (int fm = 0; fm < 4; ++fm) {
      int ro = (wr * 64 + fm * 16 + lm) * 8 + lg * 1024;
      fah[fm] = *(const short8*)(base + 0 * PLANESH + ro);
      fal[fm] = *(const short8*)(base + 1 * PLANESH + ro);
    }
    #pragma unroll
    for (int fn = 0; fn < 4; ++fn) {
      int ro = (wc * 64 + fn * 16 + lm) * 8 + lg * 1024;
      fbh[fn] = *(const short8*)(base + 2 * PLANESH + ro);
      fbl[fn] = *(const short8*)(base + 3 * PLANESH + ro);
    }
    #pragma unroll
    for (int fm = 0; fm < 4; ++fm)
      #pragma unroll
      for (int fn = 0; fn < 4; ++fn) {
        acc[fm][fn] = __builtin_amdgcn_mfma_f32_16x16x32_bf16(fah[fm], fbh[fn], acc[fm][fn], 0, 0, 0);
        acc[fm][fn] = __builtin_amdgcn_mfma_f32_16x16x32_bf16(fah[fm], fbl[fn], acc[fm][fn], 0, 0, 0);
        acc[fm][fn] = __builtin_amdgcn_mfma_f32_16x16x32_bf16(fal[fm], fbh[fn], acc[fm][fn], 0, 0, 0);
      }

    __syncthreads();                  // drains prefetch; cur reads complete
    cur ^= 1;
  }

  // epilogue: C layout col=lane&15, row=(lane>>4)*4+reg  [m89-verified]
  #pragma unroll
  for (int fn = 0; fn < 4; ++fn) {
    int gc = blockN + wc * 64 + fn * 16 + lm;
    float bv = bias[gc];
    float cp = 0.0f;
    #pragma unroll
    for (int fm = 0; fm < 4; ++fm) {
      int gr0 = blockM + wr * 64 + fm * 16 + lg * 4;
      #pragma unroll
      for (int j = 0; j < 4; ++j) {
        int gr = gr0 + j;
        float nrm = jax_normal(nk0, nk1, (uint32_t)(gr * N + gc));
        float v = tanh_fast(acc[fm][fn][j] + bv) + NOISE_LEVEL * nrm;
        out[(size_t)gr * N + gc] = v;
        cp += fabsf(v);
      }
    }
    cp += __shfl_xor(cp, 16);
    cp += __shfl_xor(cp, 32);
    if (lg == 0) atomicAdd(&colabs[gc], cp);
  }
#undef STAGE
}

// ---------------------------------------------------------------------------
// thermal = 0.7*prev + 0.3*(colabs*CROSSTALK); tn[i] = CROSSTALK * sum thermal[j]/(i-j)^2
// ---------------------------------------------------------------------------
__global__ __launch_bounds__(256)
void thermal_tn(const float* __restrict__ colabs, const float* __restrict__ prev_thermal,
                float* __restrict__ thermal_out, float* __restrict__ tn_out, int has_prev)
{
  __shared__ float th[2048];
  __shared__ float inv[2048];
  const int t = threadIdx.x;
  for (int j = t; j < 2048; j += 256) {
    float lt = colabs[j] * CROSSTALK;
    float pv = has_prev ? prev_thermal[j] : 0.0f;
    th[j] = 0.7f * pv + 0.3f * lt;
    float d = (float)j;
    inv[j] = (j == 0) ? 0.0f : 1.0f / (d * d);
  }
  __syncthreads();
  const int i = blockIdx.x * 256 + t;
  float s = 0.0f;
  #pragma unroll 4
  for (int j = 0; j < 2048; ++j) {
    int d = i - j; d = d < 0 ? -d : d;
    s += th[j] * inv[d];
  }
  tn_out[i] = s * CROSSTALK;
  thermal_out[i] = th[i];
}

// ---------------------------------------------------------------------------
// Final: x2 = (a2 + tn2) with coherence; out[b,:] = x2[b,:] @ Wout^T + bout
// ---------------------------------------------------------------------------
__global__ __launch_bounds__(256)
void final_out(const float* __restrict__ a2, const float* __restrict__ tn2,
               const float* __restrict__ Wout, const float* __restrict__ bout,
               float* __restrict__ out, uint32_t pk0, uint32_t pk1)
{
  const int wave = threadIdx.x >> 6;
  const int lane = threadIdx.x & 63;
  const int b = blockIdx.x * 4 + wave;
  const float* row = a2 + (size_t)b * 2048;
  float acc0 = 0.0f, acc1 = 0.0f;
  #pragma unroll
  for (int i = 0; i < 8; ++i) {
    int h = lane * 4 + i * 256;
    float4 v  = *(const float4*)&row[h];
    float4 tv = *(const float4*)&tn2[h];
    float4 w0 = *(const float4*)&Wout[h];
    float4 w1 = *(const float4*)&Wout[2048 + h];
    float xs[4]  = {v.x + tv.x, v.y + tv.y, v.z + tv.z, v.w + tv.w};
    float w0s[4] = {w0.x, w0.y, w0.z, w0.w};
    float w1s[4] = {w1.x, w1.y, w1.z, w1.w};
    uint32_t fb = (uint32_t)(b * 2048 + h);
    #pragma unroll
    for (int e = 0; e < 4; ++e) {
      float ph = COHERENCE * jax_normal(pk0, pk1, fb + e);
      float cp = cos_small(ph);
      float xv = xs[e] + (xs[e] * cp - xs[e]) * COHERENCE;
      acc0 = fmaf(xv, w0s[e], acc0);
      acc1 = fmaf(xv, w1s[e], acc1);
    }
  }
  #pragma unroll
  for (int off = 32; off > 0; off >>= 1) {
    acc0 += __shfl_down(acc0, off);
    acc1 += __shfl_down(acc1, off);
  }
  if (lane == 0) {
    out[(size_t)b * 2 + 0] = acc0 + bout[0];
    out[(size_t)b * 2 + 1] = acc1 + bout[1];
  }
}

extern "C" void kernel_launch(void* const* d_in, const int* in_sizes, int n_in,
                              void* d_out, int out_size, void* d_ws, size_t ws_size,
                              hipStream_t stream)
{
  (void)in_sizes; (void)n_in; (void)out_size; (void)ws_size;
  const float* x    = (const float*)d_in[0];
  const float* W1   = (const float*)d_in[1];
  const float* b1   = (const float*)d_in[2];
  const float* W2   = (const float*)d_in[3];
  const float* b2   = (const float*)d_in[4];
  const float* Wout = (const float*)d_in[5];
  const float* bout = (const float*)d_in[6];
  float* out = (float*)d_out;

  const int M = 8192, H = 2048, Din = 1024;
  const size_t MB64 = (size_t)64 * 1024 * 1024;

  char* ws = (char*)d_ws;
  // P0 [0,64MB): a1 fp32 (GEMM1 out), later reused as a2 fp32 (GEMM2 out)
  float* a_f32 = (float*)ws;
  // P1 [64MB,128MB): first xth/xtl (GEMM1 A planes), then a1h/a1l (GEMM2 A planes)
  unsigned short* p1  = (unsigned short*)(ws + MB64);
  unsigned short* xth = p1;
  unsigned short* xtl = p1 + (size_t)M * Din;
  unsigned short* a1h = p1;
  unsigned short* a1l = p1 + (size_t)M * H;
  // P2 [128MB,152MB): W planes (packed layout)
  unsigned short* wp  = (unsigned short*)(ws + 2 * MB64);
  unsigned short* W1h = wp;
  unsigned short* W1l = wp + (size_t)H * Din;
  unsigned short* W2h = wp + (size_t)2 * H * Din;
  unsigned short* W2l = wp + (size_t)2 * H * Din + (size_t)H * H;
  // small arrays
  float* small = (float*)(ws + 2 * MB64 + (size_t)24 * 1024 * 1024);
  float* colabs1  = small + 0 * H;
  float* colabs2  = small + 1 * H;
  float* thermal1 = small + 2 * H;
  float* thermal2 = small + 3 * H;
  float* tn1      = small + 4 * H;
  float* tn2      = small + 5 * H;

  // fold_in keys: key(42) = (0,42); fold_in(key, d) = threefry(key, [0,d])
  uint32_t kn0a, kn0b, kp0a, kp0b, kn1a, kn1b, kp1a, kp1b;
  threefry2x32(0u, 42u, 0u, 0u, kn0a, kn0b);   // noise, layer 0
  threefry2x32(0u, 42u, 0u, 1u, kp0a, kp0b);   // phase, layer 0
  threefry2x32(0u, 42u, 0u, 2u, kn1a, kn1b);   // noise, layer 1
  threefry2x32(0u, 42u, 0u, 3u, kp1a, kp1b);   // phase, layer 1

  hipMemsetAsync(colabs1, 0, 2 * H * sizeof(float), stream);

  // pre-split + pack passes (kshift = log2(K/32))
  split_pack<<<2048, 256, 0, stream>>>(W1, W1h, W1l, H, Din, 5, 0);
  split_pack<<<2048, 256, 0, stream>>>(W2, W2h, W2l, H, H, 6, 0);
  split_pack<<<2048, 256, 0, stream>>>(x, xth, xtl, M, Din, 5, 1);

  const int nblk = (M / BM) * (H / BN);   // 64*16 = 1024 (multiple of 8)
  gemm_mfma<<<nblk, 256, 0, stream>>>(xth, xtl, W1h, W1l, b1, a_f32, colabs1,
                                      M, H, Din, kn0a, kn0b);
  thermal_tn<<<H / 256, 256, 0, stream>>>(colabs1, nullptr, thermal1, tn1, 0);
  coherence_split_pack<<<2048, 256, 0, stream>>>(a_f32, tn1, a1h, a1l,
                                                 kp0a, kp0b, M, H, 6);
  gemm_mfma<<<nblk, 256, 0, stream>>>(a1h, a1l, W2h, W2l, b2, a_f32, colabs2,
                                      M, H, H, kn1a, kn1b);
  thermal_tn<<<H / 256, 256, 0, stream>>>(colabs2, thermal1, thermal2, tn2, 1);
  final_out<<<M / 4, 256, 0, stream>>>(a_f32, tn2, Wout, bout, out, kp1a, kp1b);
}

// Round 7
// 461.153 us; speedup vs baseline: 2.2538x; 1.2310x over previous
//
#include <hip/hip_runtime.h>
#include <stdint.h>
#include <math.h>

#define NOISE_LEVEL 0.02f
#define CROSSTALK   0.05f
#define COHERENCE   0.03f

typedef _Float16 half8 __attribute__((ext_vector_type(8)));
typedef __attribute__((ext_vector_type(4))) float f32x4;

#define TF_ROUND(x0,x1,R) { x0 += x1; x1 = ((x1 << (R)) | (x1 >> (32-(R)))); x1 ^= x0; }

__host__ __device__ inline void threefry2x32(uint32_t k0, uint32_t k1,
                                             uint32_t x0, uint32_t x1,
                                             uint32_t& o0, uint32_t& o1)
{
  uint32_t ks2 = k0 ^ k1 ^ 0x1BD11BDAu;
  x0 += k0; x1 += k1;
  TF_ROUND(x0,x1,13) TF_ROUND(x0,x1,15) TF_ROUND(x0,x1,26) TF_ROUND(x0,x1,6)
  x0 += k1; x1 += ks2 + 1u;
  TF_ROUND(x0,x1,17) TF_ROUND(x0,x1,29) TF_ROUND(x0,x1,16) TF_ROUND(x0,x1,24)
  x0 += ks2; x1 += k0 + 2u;
  TF_ROUND(x0,x1,13) TF_ROUND(x0,x1,15) TF_ROUND(x0,x1,26) TF_ROUND(x0,x1,6)
  x0 += k0; x1 += k1 + 3u;
  TF_ROUND(x0,x1,17) TF_ROUND(x0,x1,29) TF_ROUND(x0,x1,16) TF_ROUND(x0,x1,24)
  x0 += k1; x1 += ks2 + 4u;
  TF_ROUND(x0,x1,13) TF_ROUND(x0,x1,15) TF_ROUND(x0,x1,26) TF_ROUND(x0,x1,6)
  o0 = x0 + ks2; o1 = x1 + k0 + 5u;
}

// threefry_partitionable bits for 32-bit draws: XOR of the two output words.
__device__ inline uint32_t jax_bits(uint32_t k0, uint32_t k1, uint32_t idx)
{
  uint32_t o0, o1; threefry2x32(k0, k1, 0u, idx, o0, o1); return o0 ^ o1;
}

// JAX random.normal(float32): u ~ uniform[-0.99999994, 1); n = sqrt(2)*erfinv(u)
__device__ inline float jax_normal(uint32_t k0, uint32_t k1, uint32_t idx)
{
  uint32_t bits = jax_bits(k0, k1, idx);
  float f = __uint_as_float((bits >> 9) | 0x3f800000u) - 1.0f;   // [0,1)
  float u = fmaf(f, 2.0f, -0.99999994f);
  u = fmaxf(-0.99999994f, u);
  float w = -__logf(fmaf(-u, u, 1.0f));
  float p;
  if (w < 5.0f) {
    w -= 2.5f;
    p = 2.81022636e-08f;
    p = fmaf(p, w, 3.43273939e-07f);
    p = fmaf(p, w, -3.5233877e-06f);
    p = fmaf(p, w, -4.39150654e-06f);
    p = fmaf(p, w, 0.00021858087f);
    p = fmaf(p, w, -0.00125372503f);
    p = fmaf(p, w, -0.00417768164f);
    p = fmaf(p, w, 0.246640727f);
    p = fmaf(p, w, 1.50140941f);
  } else {
    w = sqrtf(w) - 3.0f;
    p = -0.000200214257f;
    p = fmaf(p, w, 0.000100950558f);
    p = fmaf(p, w, 0.00134934322f);
    p = fmaf(p, w, -0.00367342844f);
    p = fmaf(p, w, 0.00573950773f);
    p = fmaf(p, w, -0.0076224613f);
    p = fmaf(p, w, 0.00943887047f);
    p = fmaf(p, w, 1.00167406f);
    p = fmaf(p, w, 2.83297682f);
  }
  return 1.41421354f * (p * u);
}

__device__ inline float cos_small(float p)
{
  float p2 = p * p;
  return 1.0f + p2 * (-0.5f + p2 * (4.16666679e-02f + p2 * (-1.38888892e-03f)));
}

// exact-algebra tanh via fast exp; abs err <= ~1.2e-7, inf-safe.
__device__ inline float tanh_fast(float x)
{
  float ax = fabsf(x);
  float e = __expf(2.0f * ax);
  float r = 1.0f - 2.0f / (e + 1.0f);
  return copysignf(r, x);
}

// ---------------------------------------------------------------------------
// Packed fp16 plane layout (BKT=64):
//   tile (rb, kt) occupies halves [(rb*ktiles + kt)*8192, +8192)
//   within tile: [kq(8)][row(128)][8]   (kq = k-octet of the 64-wide k-tile)
// Packer thread g (8 elems, 16B store): tile=g>>10, s=g&1023, kq=s>>7,
// row=s&127 -> writes fully coalesced at out+g*8.
// ---------------------------------------------------------------------------

// pack_plane: fp32 [R][K] -> packed fp16 plane (optional tanh first).
__global__ __launch_bounds__(256)
void pack_plane(const float* __restrict__ in, _Float16* __restrict__ out,
                int R, int K, int kshift, int do_tanh)
{
  const int nslots = R * (K >> 3);
  const int ktm = (K >> 6) - 1;
  int g = blockIdx.x * 256 + threadIdx.x;
  const int stride = gridDim.x * 256;
  for (; g < nslots; g += stride) {
    int tile = g >> 10;
    int s = g & 1023;
    int kq = s >> 7, row = s & 127;
    int rb = tile >> kshift, kt = tile & ktm;
    int r = rb * 128 + row;
    int k = kt * 64 + kq * 8;
    const float* src = in + (size_t)r * K + k;
    float4 v0 = *(const float4*)src;
    float4 v1 = *(const float4*)(src + 4);
    float xs[8] = {v0.x, v0.y, v0.z, v0.w, v1.x, v1.y, v1.z, v1.w};
    half8 h;
    #pragma unroll
    for (int e = 0; e < 8; ++e) {
      float x = do_tanh ? tanh_fast(xs[e]) : xs[e];
      h[e] = (_Float16)x;     // v_cvt_f16_f32, RN
    }
    *(half8*)&out[(size_t)g * 8] = h;
  }
}

// coherence + thermal-decompose + pack:
//   full = (x + tn) with phase interference;  small = full - tn[col]  -> fp16.
// The constant tn part is folded into the GEMM bias by bias_fold (exact).
__global__ __launch_bounds__(256)
void coherence_pack_small(const float* __restrict__ x, const float* __restrict__ tn,
                          _Float16* __restrict__ out,
                          uint32_t pk0, uint32_t pk1, int R, int K, int kshift)
{
  const int nslots = R * (K >> 3);
  const int ktm = (K >> 6) - 1;
  int g = blockIdx.x * 256 + threadIdx.x;
  const int stride = gridDim.x * 256;
  for (; g < nslots; g += stride) {
    int tile = g >> 10;
    int s = g & 1023;
    int kq = s >> 7, row = s & 127;
    int rb = tile >> kshift, kt = tile & ktm;
    int r = rb * 128 + row;
    int k = kt * 64 + kq * 8;
    const float* src = x + (size_t)r * K + k;
    float4 v0 = *(const float4*)src;
    float4 v1 = *(const float4*)(src + 4);
    float4 t0 = *(const float4*)&tn[k];
    float4 t1 = *(const float4*)&tn[k + 4];
    float vv[8] = {v0.x + t0.x, v0.y + t0.y, v0.z + t0.z, v0.w + t0.w,
                   v1.x + t1.x, v1.y + t1.y, v1.z + t1.z, v1.w + t1.w};
    float ts[8] = {t0.x, t0.y, t0.z, t0.w, t1.x, t1.y, t1.z, t1.w};
    uint32_t fb = (uint32_t)(r * K + k);
    half8 h;
    #pragma unroll
    for (int e = 0; e < 8; ++e) {
      float ph = COHERENCE * jax_normal(pk0, pk1, fb + e);
      float cp = cos_small(ph);
      float xv = vv[e] + (vv[e] * cp - vv[e]) * COHERENCE;
      h[e] = (_Float16)(xv - ts[e]);
    }
    *(half8*)&out[(size_t)g * 8] = h;
  }
}

// bias_fold: fold[j] = b[j] + sum_h tn[h] * W[j,h]   (fp32, one wave per j)
__global__ __launch_bounds__(256)
void bias_fold(const float* __restrict__ tn, const float* __restrict__ W,
               const float* __restrict__ b, float* __restrict__ fold, int K)
{
  const int wid = threadIdx.x >> 6;
  const int lane = threadIdx.x & 63;
  const int j = blockIdx.x * 4 + wid;
  const float* row = W + (size_t)j * K;
  float s = 0.0f;
  for (int h = lane; h < K; h += 64) s = fmaf(tn[h], row[h], s);
  #pragma unroll
  for (int off = 32; off > 0; off >>= 1) s += __shfl_down(s, off);
  if (lane == 0) fold[j] = b[j] + s;
}

// ---------------------------------------------------------------------------
// Single-plane fp16 MFMA GEMM on packed planes:
//   out = tanh(A @ W^T + bias) + 0.02*normal(key, r*N+c); colabs += sum|v|.
// 128x128 tile, BKT=64, 4 waves, double-buffered 2-phase; staging = straight
// contiguous copy of one 16KB tile per operand (16 x global_load_lds 1KB,
// fully coalesced, linear LDS dest). Fragment ds_read_b128 conflict-free
// (same [kq][row][8] structure as R6, measured 0 conflicts).
// Grid: bn-minor decode + bijective XCD swizzle (nwg % 8 == 0).
// ---------------------------------------------------------------------------
#define BM 128
#define BN 128
#define BKT 64
#define TILEH 8192            // halves per operand tile (128*64)
#define BUFH  (2 * TILEH)     // halves per buffer (A,B)

__global__ __launch_bounds__(256)
void gemm_f16(const _Float16* __restrict__ Ap, const _Float16* __restrict__ Bp,
              const float* __restrict__ bias, float* __restrict__ out,
              float* __restrict__ colabs, int M, int N, int K,
              uint32_t nk0, uint32_t nk1)
{
  __shared__ __align__(16) _Float16 lds[2 * BUFH];   // 64 KiB

  const int t = threadIdx.x;
  const int nwg = gridDim.x;
  const int wg = (blockIdx.x & 7) * (nwg >> 3) + (blockIdx.x >> 3);
  const int nbn = N / BN;
  const int bn = wg & (nbn - 1);       // bn-minor: consecutive wgs share A panel
  const int bm = wg / nbn;
  const int blockM = bm * BM, blockN = bn * BN;

  const int lane = t & 63;
  const int w = t >> 6;
  const int wr = w >> 1, wc = w & 1;
  const int lm = lane & 15, lg = lane >> 4;

  // staging: wave w copies half an operand tile (8 KiB = 8 x 1KiB insts)
  const int op = w >> 1;               // 0 = A, 1 = B
  const int part = w & 1;              // which 8KB half of the 16KB tile
  const _Float16* gplane = op ? Bp : Ap;
  const int blk = op ? bn : bm;
  const int ktiles = K >> 6;
  const _Float16* gsrc0 = gplane + ((size_t)blk * ktiles) * TILEH
                          + part * (TILEH / 2) + lane * 8;
  _Float16* lbase = lds + op * TILEH + part * (TILEH / 2);

#define STAGE(buf, kt_) {                                                      \
    _Float16* lp = lbase + (buf) * BUFH;                                       \
    const _Float16* s = gsrc0 + (size_t)(kt_) * TILEH;                         \
    _Pragma("unroll")                                                          \
    for (int i = 0; i < 8; ++i)                                                \
      __builtin_amdgcn_global_load_lds((const void*)(s + i * 512),             \
                                       (void*)(lp + i * 512), 16, 0, 0);       \
  }

  f32x4 acc[4][4];
  #pragma unroll
  for (int i = 0; i < 4; ++i)
    #pragma unroll
    for (int j = 0; j < 4; ++j) acc[i][j] = 0.0f;

  const int nk = ktiles;
  STAGE(0, 0);
  __syncthreads();                    // vmcnt(0)+barrier: buf0 ready
  int cur = 0;

  for (int kt = 0; kt < nk; ++kt) {
    if (kt + 1 < nk) STAGE(cur ^ 1, kt + 1);   // prefetch overlaps compute

    const _Float16* base = lds + cur * BUFH;
    #pragma unroll
    for (int ks = 0; ks < 2; ++ks) {
      half8 fa[4], fb[4];
      const int kq = ks * 4 + lg;
      #pragma unroll
      for (int fm = 0; fm < 4; ++fm)
        fa[fm] = *(const half8*)(base + kq * 1024 + (wr * 64 + fm * 16 + lm) * 8);
      #pragma unroll
      for (int fn = 0; fn < 4; ++fn)
        fb[fn] = *(const half8*)(base + TILEH + kq * 1024 + (wc * 64 + fn * 16 + lm) * 8);
      #pragma unroll
      for (int fm = 0; fm < 4; ++fm)
        #pragma unroll
        for (int fn = 0; fn < 4; ++fn)
          acc[fm][fn] = __builtin_amdgcn_mfma_f32_16x16x32_f16(fa[fm], fb[fn], acc[fm][fn], 0, 0, 0);
    }

    __syncthreads();                  // drains prefetch; cur reads complete
    cur ^= 1;
  }

  // epilogue: C layout col=lane&15, row=(lane>>4)*4+reg  [m89-verified]
  #pragma unroll
  for (int fn = 0; fn < 4; ++fn) {
    int gc = blockN + wc * 64 + fn * 16 + lm;
    float bv = bias[gc];
    float cp = 0.0f;
    #pragma unroll
    for (int fm = 0; fm < 4; ++fm) {
      int gr0 = blockM + wr * 64 + fm * 16 + lg * 4;
      #pragma unroll
      for (int j = 0; j < 4; ++j) {
        int gr = gr0 + j;
        float nrm = jax_normal(nk0, nk1, (uint32_t)(gr * N + gc));
        float v = tanh_fast(acc[fm][fn][j] + bv) + NOISE_LEVEL * nrm;
        out[(size_t)gr * N + gc] = v;
        cp += fabsf(v);
      }
    }
    cp += __shfl_xor(cp, 16);
    cp += __shfl_xor(cp, 32);
    if (lg == 0) atomicAdd(&colabs[gc], cp);
  }
#undef STAGE
}

// ---------------------------------------------------------------------------
// thermal = 0.7*prev + 0.3*(colabs*CROSSTALK); tn[i] = CROSSTALK * sum thermal[j]/(i-j)^2
// ---------------------------------------------------------------------------
__global__ __launch_bounds__(256)
void thermal_tn(const float* __restrict__ colabs, const float* __restrict__ prev_thermal,
                float* __restrict__ thermal_out, float* __restrict__ tn_out, int has_prev)
{
  __shared__ float th[2048];
  __shared__ float inv[2048];
  const int t = threadIdx.x;
  for (int j = t; j < 2048; j += 256) {
    float lt = colabs[j] * CROSSTALK;
    float pv = has_prev ? prev_thermal[j] : 0.0f;
    th[j] = 0.7f * pv + 0.3f * lt;
    float d = (float)j;
    inv[j] = (j == 0) ? 0.0f : 1.0f / (d * d);
  }
  __syncthreads();
  const int i = blockIdx.x * 256 + t;
  float s = 0.0f;
  #pragma unroll 4
  for (int j = 0; j < 2048; ++j) {
    int d = i - j; d = d < 0 ? -d : d;
    s += th[j] * inv[d];
  }
  tn_out[i] = s * CROSSTALK;
  thermal_out[i] = th[i];
}

// ---------------------------------------------------------------------------
// Final: x2 = (a2 + tn2) with coherence; out[b,:] = x2[b,:] @ Wout^T + bout
// ---------------------------------------------------------------------------
__global__ __launch_bounds__(256)
void final_out(const float* __restrict__ a2, const float* __restrict__ tn2,
               const float* __restrict__ Wout, const float* __restrict__ bout,
               float* __restrict__ out, uint32_t pk0, uint32_t pk1)
{
  const int wave = threadIdx.x >> 6;
  const int lane = threadIdx.x & 63;
  const int b = blockIdx.x * 4 + wave;
  const float* row = a2 + (size_t)b * 2048;
  float acc0 = 0.0f, acc1 = 0.0f;
  #pragma unroll
  for (int i = 0; i < 8; ++i) {
    int h = lane * 4 + i * 256;
    float4 v  = *(const float4*)&row[h];
    float4 tv = *(const float4*)&tn2[h];
    float4 w0 = *(const float4*)&Wout[h];
    float4 w1 = *(const float4*)&Wout[2048 + h];
    float xs[4]  = {v.x + tv.x, v.y + tv.y, v.z + tv.z, v.w + tv.w};
    float w0s[4] = {w0.x, w0.y, w0.z, w0.w};
    float w1s[4] = {w1.x, w1.y, w1.z, w1.w};
    uint32_t fb = (uint32_t)(b * 2048 + h);
    #pragma unroll
    for (int e = 0; e < 4; ++e) {
      float ph = COHERENCE * jax_normal(pk0, pk1, fb + e);
      float cp = cos_small(ph);
      float xv = xs[e] + (xs[e] * cp - xs[e]) * COHERENCE;
      acc0 = fmaf(xv, w0s[e], acc0);
      acc1 = fmaf(xv, w1s[e], acc1);
    }
  }
  #pragma unroll
  for (int off = 32; off > 0; off >>= 1) {
    acc0 += __shfl_down(acc0, off);
    acc1 += __shfl_down(acc1, off);
  }
  if (lane == 0) {
    out[(size_t)b * 2 + 0] = acc0 + bout[0];
    out[(size_t)b * 2 + 1] = acc1 + bout[1];
  }
}

extern "C" void kernel_launch(void* const* d_in, const int* in_sizes, int n_in,
                              void* d_out, int out_size, void* d_ws, size_t ws_size,
                              hipStream_t stream)
{
  (void)in_sizes; (void)n_in; (void)out_size; (void)ws_size;
  const float* x    = (const float*)d_in[0];
  const float* W1   = (const float*)d_in[1];
  const float* b1   = (const float*)d_in[2];
  const float* W2   = (const float*)d_in[3];
  const float* b2   = (const float*)d_in[4];
  const float* Wout = (const float*)d_in[5];
  const float* bout = (const float*)d_in[6];
  float* out = (float*)d_out;

  const int M = 8192, H = 2048, Din = 1024;
  const size_t MB = (size_t)1024 * 1024;

  char* ws = (char*)d_ws;
  // [0,64MB): a_f32 (GEMM1 out fp32, later GEMM2 out fp32)
  float* a_f32 = (float*)ws;
  // [64MB,96MB): packed fp16 A operand (16MB for G1's tanh(x); then 32MB for G2's small)
  _Float16* Apk = (_Float16*)(ws + 64 * MB);
  // [96MB,100MB): W1 packed fp16; [100MB,108MB): W2 packed fp16
  _Float16* W1p = (_Float16*)(ws + 96 * MB);
  _Float16* W2p = (_Float16*)(ws + 100 * MB);
  // [108MB, ...): small arrays
  float* small = (float*)(ws + 108 * MB);
  float* colabs1  = small + 0 * H;
  float* colabs2  = small + 1 * H;
  float* thermal1 = small + 2 * H;
  float* thermal2 = small + 3 * H;
  float* tn1      = small + 4 * H;
  float* tn2      = small + 5 * H;
  float* foldb    = small + 6 * H;

  // fold_in keys: key(42) = (0,42); fold_in(key, d) = threefry(key, [0,d])
  uint32_t kn0a, kn0b, kp0a, kp0b, kn1a, kn1b, kp1a, kp1b;
  threefry2x32(0u, 42u, 0u, 0u, kn0a, kn0b);   // noise, layer 0
  threefry2x32(0u, 42u, 0u, 1u, kp0a, kp0b);   // phase, layer 0
  threefry2x32(0u, 42u, 0u, 2u, kn1a, kn1b);   // noise, layer 1
  threefry2x32(0u, 42u, 0u, 3u, kp1a, kp1b);   // phase, layer 1

  hipMemsetAsync(colabs1, 0, 2 * H * sizeof(float), stream);

  // packs (kshift = log2(K/64))
  pack_plane<<<1024, 256, 0, stream>>>(W1, W1p, H, Din, 4, 0);
  pack_plane<<<2048, 256, 0, stream>>>(W2, W2p, H, H, 5, 0);
  pack_plane<<<2048, 256, 0, stream>>>(x, Apk, M, Din, 4, 1);

  const int nblk = (M / BM) * (H / BN);   // 64*16 = 1024 (multiple of 8)
  gemm_f16<<<nblk, 256, 0, stream>>>(Apk, W1p, b1, a_f32, colabs1,
                                     M, H, Din, kn0a, kn0b);
  thermal_tn<<<H / 256, 256, 0, stream>>>(colabs1, nullptr, thermal1, tn1, 0);
  bias_fold<<<H / 4, 256, 0, stream>>>(tn1, W2, b2, foldb, H);
  coherence_pack_small<<<2048, 256, 0, stream>>>(a_f32, tn1, Apk,
                                                 kp0a, kp0b, M, H, 5);
  gemm_f16<<<nblk, 256, 0, stream>>>(Apk, W2p, foldb, a_f32, colabs2,
                                     M, H, H, kn1a, kn1b);
  thermal_tn<<<H / 256, 256, 0, stream>>>(colabs2, thermal1, thermal2, tn2, 1);
  final_out<<<M / 4, 256, 0, stream>>>(a_f32, tn2, Wout, bout, out, kp1a, kp1b);
}

// Round 8
// 430.511 us; speedup vs baseline: 2.4142x; 1.0712x over previous
//
#include <hip/hip_runtime.h>
#include <stdint.h>
#include <math.h>

#define NOISE_LEVEL 0.02f
#define CROSSTALK   0.05f
#define COHERENCE   0.03f

typedef _Float16 half8 __attribute__((ext_vector_type(8)));
typedef _Float16 half4 __attribute__((ext_vector_type(4)));
typedef __attribute__((ext_vector_type(4))) float f32x4;

#define TF_ROUND(x0,x1,R) { x0 += x1; x1 = ((x1 << (R)) | (x1 >> (32-(R)))); x1 ^= x0; }

__host__ __device__ inline void threefry2x32(uint32_t k0, uint32_t k1,
                                             uint32_t x0, uint32_t x1,
                                             uint32_t& o0, uint32_t& o1)
{
  uint32_t ks2 = k0 ^ k1 ^ 0x1BD11BDAu;
  x0 += k0; x1 += k1;
  TF_ROUND(x0,x1,13) TF_ROUND(x0,x1,15) TF_ROUND(x0,x1,26) TF_ROUND(x0,x1,6)
  x0 += k1; x1 += ks2 + 1u;
  TF_ROUND(x0,x1,17) TF_ROUND(x0,x1,29) TF_ROUND(x0,x1,16) TF_ROUND(x0,x1,24)
  x0 += ks2; x1 += k0 + 2u;
  TF_ROUND(x0,x1,13) TF_ROUND(x0,x1,15) TF_ROUND(x0,x1,26) TF_ROUND(x0,x1,6)
  x0 += k0; x1 += k1 + 3u;
  TF_ROUND(x0,x1,17) TF_ROUND(x0,x1,29) TF_ROUND(x0,x1,16) TF_ROUND(x0,x1,24)
  x0 += k1; x1 += ks2 + 4u;
  TF_ROUND(x0,x1,13) TF_ROUND(x0,x1,15) TF_ROUND(x0,x1,26) TF_ROUND(x0,x1,6)
  o0 = x0 + ks2; o1 = x1 + k0 + 5u;
}

// threefry_partitionable bits for 32-bit draws: XOR of the two output words.
__device__ inline uint32_t jax_bits(uint32_t k0, uint32_t k1, uint32_t idx)
{
  uint32_t o0, o1; threefry2x32(k0, k1, 0u, idx, o0, o1); return o0 ^ o1;
}

// JAX random.normal(float32): u ~ uniform[-0.99999994, 1); n = sqrt(2)*erfinv(u)
__device__ inline float jax_normal(uint32_t k0, uint32_t k1, uint32_t idx)
{
  uint32_t bits = jax_bits(k0, k1, idx);
  float f = __uint_as_float((bits >> 9) | 0x3f800000u) - 1.0f;   // [0,1)
  float u = fmaf(f, 2.0f, -0.99999994f);
  u = fmaxf(-0.99999994f, u);
  float w = -__logf(fmaf(-u, u, 1.0f));
  float p;
  if (w < 5.0f) {
    w -= 2.5f;
    p = 2.81022636e-08f;
    p = fmaf(p, w, 3.43273939e-07f);
    p = fmaf(p, w, -3.5233877e-06f);
    p = fmaf(p, w, -4.39150654e-06f);
    p = fmaf(p, w, 0.00021858087f);
    p = fmaf(p, w, -0.00125372503f);
    p = fmaf(p, w, -0.00417768164f);
    p = fmaf(p, w, 0.246640727f);
    p = fmaf(p, w, 1.50140941f);
  } else {
    w = sqrtf(w) - 3.0f;
    p = -0.000200214257f;
    p = fmaf(p, w, 0.000100950558f);
    p = fmaf(p, w, 0.00134934322f);
    p = fmaf(p, w, -0.00367342844f);
    p = fmaf(p, w, 0.00573950773f);
    p = fmaf(p, w, -0.0076224613f);
    p = fmaf(p, w, 0.00943887047f);
    p = fmaf(p, w, 1.00167406f);
    p = fmaf(p, w, 2.83297682f);
  }
  return 1.41421354f * (p * u);
}

__device__ inline float cos_small(float p)
{
  float p2 = p * p;
  return 1.0f + p2 * (-0.5f + p2 * (4.16666679e-02f + p2 * (-1.38888892e-03f)));
}

// exact-algebra tanh via fast exp; abs err <= ~1.2e-7, inf-safe.
__device__ inline float tanh_fast(float x)
{
  float ax = fabsf(x);
  float e = __expf(2.0f * ax);
  float r = 1.0f - 2.0f / (e + 1.0f);
  return copysignf(r, x);
}

// ---------------------------------------------------------------------------
// Packed fp16 A/W operand layout (BKT=64): tile (rb,kt) at
//   halves [(rb*ktiles + kt)*8192, +8192), internally [kq(8)][row(128)][8].
// Fragment-native fp16 OUTPUT layout (C of a 128x128 block):
//   idx = (tile16*4 + w)*4096 + (fn*16+fm*4+j)*64 + lane,
//   tile16 = bm*16 + bn, w = wr*2+wc, lane = lg*16+lm,
//   row = bm*128 + wr*64 + fm*16 + lg*4 + j, col = bn*128 + wc*64 + fn*16 + lm.
// Every epilogue store = 64 lanes x 2B = one full 128B line.
// ---------------------------------------------------------------------------

// pack_plane: fp32 [R][K] -> packed fp16 operand plane (optional tanh first).
__global__ __launch_bounds__(256)
void pack_plane(const float* __restrict__ in, _Float16* __restrict__ out,
                int R, int K, int kshift, int do_tanh)
{
  const int nslots = R * (K >> 3);
  const int ktm = (K >> 6) - 1;
  int g = blockIdx.x * 256 + threadIdx.x;
  const int stride = gridDim.x * 256;
  for (; g < nslots; g += stride) {
    int tile = g >> 10;
    int s = g & 1023;
    int kq = s >> 7, row = s & 127;
    int rb = tile >> kshift, kt = tile & ktm;
    int r = rb * 128 + row;
    int k = kt * 64 + kq * 8;
    const float* src = in + (size_t)r * K + k;
    float4 v0 = *(const float4*)src;
    float4 v1 = *(const float4*)(src + 4);
    float xs[8] = {v0.x, v0.y, v0.z, v0.w, v1.x, v1.y, v1.z, v1.w};
    half8 h;
    #pragma unroll
    for (int e = 0; e < 8; ++e) {
      float x = do_tanh ? tanh_fast(xs[e]) : xs[e];
      h[e] = (_Float16)x;
    }
    *(half8*)&out[(size_t)g * 8] = h;
  }
}

// decode fragment-native index for (r, c) with 16 col-blocks (N=2048)
__device__ __forceinline__ size_t cnat_idx(int r, int c)
{
  int bm = r >> 7, bn = c >> 7, rr = r & 127, cc = c & 127;
  int w = ((rr >> 6) << 1) | (cc >> 6);
  int fm = (rr >> 4) & 3, lg = (rr >> 2) & 3, j = rr & 3;
  int fn = (cc >> 4) & 3, lm = cc & 15;
  return (((size_t)(bm * 16 + bn) * 4 + w) * 4096)
         + (size_t)(fn * 16 + fm * 4 + j) * 64 + lg * 16 + lm;
}

// coherence + thermal-decompose + pack: reads G1 out (fragment-native fp16),
// full = (x + tn) with phase interference; small = full - tn[col] -> packed fp16.
__global__ __launch_bounds__(256)
void coherence_pack_small(const _Float16* __restrict__ xn, const float* __restrict__ tn,
                          _Float16* __restrict__ out,
                          uint32_t pk0, uint32_t pk1, int R, int K, int kshift)
{
  const int nslots = R * (K >> 3);
  const int ktm = (K >> 6) - 1;
  int g = blockIdx.x * 256 + threadIdx.x;
  const int stride = gridDim.x * 256;
  for (; g < nslots; g += stride) {
    int tile = g >> 10;
    int s = g & 1023;
    int kq = s >> 7, row = s & 127;
    int rb = tile >> kshift, kt = tile & ktm;
    int r = rb * 128 + row;
    int k = kt * 64 + kq * 8;
    half8 xv = *(const half8*)&xn[cnat_idx(r, k)];   // 8 consecutive cols
    float4 t0 = *(const float4*)&tn[k];
    float4 t1 = *(const float4*)&tn[k + 4];
    float ts[8] = {t0.x, t0.y, t0.z, t0.w, t1.x, t1.y, t1.z, t1.w};
    uint32_t fb = (uint32_t)(r * K + k);
    half8 h;
    #pragma unroll
    for (int e = 0; e < 8; ++e) {
      float vv = (float)xv[e] + ts[e];
      float ph = COHERENCE * jax_normal(pk0, pk1, fb + e);
      float cp = cos_small(ph);
      float xvv = vv + (vv * cp - vv) * COHERENCE;
      h[e] = (_Float16)(xvv - ts[e]);
    }
    *(half8*)&out[(size_t)g * 8] = h;
  }
}

// bias_fold: fold[j] = b[j] + sum_h tn[h] * W[j,h]   (fp32, one wave per j)
__global__ __launch_bounds__(256)
void bias_fold(const float* __restrict__ tn, const float* __restrict__ W,
               const float* __restrict__ b, float* __restrict__ fold, int K)
{
  const int wid = threadIdx.x >> 6;
  const int lane = threadIdx.x & 63;
  const int j = blockIdx.x * 4 + wid;
  const float* row = W + (size_t)j * K;
  float s = 0.0f;
  for (int h = lane; h < K; h += 64) s = fmaf(tn[h], row[h], s);
  #pragma unroll
  for (int off = 32; off > 0; off >>= 1) s += __shfl_down(s, off);
  if (lane == 0) fold[j] = b[j] + s;
}

// ---------------------------------------------------------------------------
// Single-plane fp16 MFMA GEMM with in-loop RNG and fragment-native fp16 out:
//   out = tanh(A @ W^T + bias) + 0.02*normal(key, r*N+c); colabs += sum|v|.
// 128x128 tile, BKT=64, 4 waves, double-buffered. The 64 noise normals per
// thread are computed as 16 f32x4 groups spread across the first 16 k-steps
// (switch-assigned to named regs - no runtime reg indexing), overlapping the
// MFMA pipe instead of serializing after the loop.
// ---------------------------------------------------------------------------
#define BM 128
#define BN 128
#define TILEH 8192            // halves per operand tile (128*64)
#define BUFH  (2 * TILEH)

__device__ __forceinline__ f32x4 noise_group(int g, int blockM, int blockN,
                                             int wr, int wc, int lg, int lm,
                                             int N, uint32_t k0, uint32_t k1)
{
  int fn = g >> 2, fm = g & 3;
  int gr0 = blockM + wr * 64 + fm * 16 + lg * 4;
  int gc  = blockN + wc * 64 + fn * 16 + lm;
  f32x4 r;
  #pragma unroll
  for (int j = 0; j < 4; ++j)
    r[j] = jax_normal(k0, k1, (uint32_t)((gr0 + j) * N + gc));
  return r;
}

__global__ __launch_bounds__(256)
void gemm_f16(const _Float16* __restrict__ Ap, const _Float16* __restrict__ Bp,
              const float* __restrict__ bias, _Float16* __restrict__ outn,
              float* __restrict__ colabs, int M, int N, int K,
              uint32_t nk0, uint32_t nk1)
{
  __shared__ __align__(16) _Float16 lds[2 * BUFH];   // 64 KiB

  const int t = threadIdx.x;
  const int nwg = gridDim.x;
  const int wg = (blockIdx.x & 7) * (nwg >> 3) + (blockIdx.x >> 3);
  const int nbn = N / BN;
  const int bn = wg & (nbn - 1);       // bn-minor: consecutive wgs share A panel
  const int bm = wg / nbn;
  const int blockM = bm * BM, blockN = bn * BN;

  const int lane = t & 63;
  const int w = t >> 6;
  const int wr = w >> 1, wc = w & 1;
  const int lm = lane & 15, lg = lane >> 4;

  // staging: wave w copies half an operand tile (8 KiB = 8 x 1KiB insts)
  const int op = w >> 1;               // 0 = A, 1 = B
  const int part = w & 1;
  const _Float16* gplane = op ? Bp : Ap;
  const int blk = op ? bn : bm;
  const int ktiles = K >> 6;
  const _Float16* gsrc0 = gplane + ((size_t)blk * ktiles) * TILEH
                          + part * (TILEH / 2) + lane * 8;
  _Float16* lbase = lds + op * TILEH + part * (TILEH / 2);

#define STAGE(buf, kt_) {                                                      \
    _Float16* lp = lbase + (buf) * BUFH;                                       \
    const _Float16* s = gsrc0 + (size_t)(kt_) * TILEH;                         \
    _Pragma("unroll")                                                          \
    for (int i = 0; i < 8; ++i)                                                \
      __builtin_amdgcn_global_load_lds((const void*)(s + i * 512),             \
                                       (void*)(lp + i * 512), 16, 0, 0);       \
  }

  f32x4 acc[4][4];
  #pragma unroll
  for (int i = 0; i < 4; ++i)
    #pragma unroll
    for (int j = 0; j < 4; ++j) acc[i][j] = 0.0f;

  f32x4 nz0 = 0.0f, nz1 = 0.0f, nz2 = 0.0f, nz3 = 0.0f;
  f32x4 nz4 = 0.0f, nz5 = 0.0f, nz6 = 0.0f, nz7 = 0.0f;
  f32x4 nz8 = 0.0f, nz9 = 0.0f, nz10 = 0.0f, nz11 = 0.0f;
  f32x4 nz12 = 0.0f, nz13 = 0.0f, nz14 = 0.0f, nz15 = 0.0f;

  const int nk = ktiles;               // 16 (G1) or 32 (G2)
  STAGE(0, 0);
  __syncthreads();
  int cur = 0;

  for (int kt = 0; kt < nk; ++kt) {
    if (kt + 1 < nk) STAGE(cur ^ 1, kt + 1);

    const _Float16* base = lds + cur * BUFH;
    #pragma unroll
    for (int ks = 0; ks < 2; ++ks) {
      half8 fa[4], fb[4];
      const int kq = ks * 4 + lg;
      #pragma unroll
      for (int fm = 0; fm < 4; ++fm)
        fa[fm] = *(const half8*)(base + kq * 1024 + (wr * 64 + fm * 16 + lm) * 8);
      #pragma unroll
      for (int fn = 0; fn < 4; ++fn)
        fb[fn] = *(const half8*)(base + TILEH + kq * 1024 + (wc * 64 + fn * 16 + lm) * 8);
      #pragma unroll
      for (int fm = 0; fm < 4; ++fm)
        #pragma unroll
        for (int fn = 0; fn < 4; ++fn)
          acc[fm][fn] = __builtin_amdgcn_mfma_f32_16x16x32_f16(fa[fm], fb[fn], acc[fm][fn], 0, 0, 0);
    }

    // in-loop RNG: one 4-normal group per step (first 16 steps); VALU overlaps
    // the MFMA pipe drain + other waves' staging. kt is wave-uniform.
    if (kt < 16) {
      f32x4 v = noise_group(kt, blockM, blockN, wr, wc, lg, lm, N, nk0, nk1);
      switch (kt) {
        case 0:  nz0  = v; break;  case 1:  nz1  = v; break;
        case 2:  nz2  = v; break;  case 3:  nz3  = v; break;
        case 4:  nz4  = v; break;  case 5:  nz5  = v; break;
        case 6:  nz6  = v; break;  case 7:  nz7  = v; break;
        case 8:  nz8  = v; break;  case 9:  nz9  = v; break;
        case 10: nz10 = v; break;  case 11: nz11 = v; break;
        case 12: nz12 = v; break;  case 13: nz13 = v; break;
        case 14: nz14 = v; break;  default: nz15 = v; break;
      }
    }

    __syncthreads();
    cur ^= 1;
  }

  // epilogue: fragment-native stores (64 lanes x 2B = one 128B line each)
  const size_t obase = (((size_t)(bm * nbn + bn) * 4 + w) * 4096) + lane;

#define EPI_STORE(fm_, fn_, NZV)                                               \
    _Pragma("unroll")                                                          \
    for (int j = 0; j < 4; ++j) {                                              \
      float v = tanh_fast(acc[fm_][fn_][j] + bv) + NOISE_LEVEL * NZV[j];       \
      outn[obase + (size_t)((fn_)*16 + (fm_)*4 + j) * 64] = (_Float16)v;       \
      cp += fabsf(v);                                                          \
    }

#define EPI_FN(fn_, NZA, NZB, NZC, NZD) {                                      \
    const int gc = blockN + wc * 64 + (fn_)*16 + lm;                           \
    const float bv = bias[gc];                                                 \
    float cp = 0.0f;                                                           \
    EPI_STORE(0, fn_, NZA) EPI_STORE(1, fn_, NZB)                              \
    EPI_STORE(2, fn_, NZC) EPI_STORE(3, fn_, NZD)                              \
    cp += __shfl_xor(cp, 16);                                                  \
    cp += __shfl_xor(cp, 32);                                                  \
    if (lg == 0) atomicAdd(&colabs[gc], cp);                                   \
  }

  EPI_FN(0, nz0,  nz1,  nz2,  nz3)
  EPI_FN(1, nz4,  nz5,  nz6,  nz7)
  EPI_FN(2, nz8,  nz9,  nz10, nz11)
  EPI_FN(3, nz12, nz13, nz14, nz15)
#undef EPI_FN
#undef EPI_STORE
#undef STAGE
}

// ---------------------------------------------------------------------------
// thermal = 0.7*prev + 0.3*(colabs*CROSSTALK); tn[i] = CROSSTALK * sum thermal[j]/(i-j)^2
// ---------------------------------------------------------------------------
__global__ __launch_bounds__(256)
void thermal_tn(const float* __restrict__ colabs, const float* __restrict__ prev_thermal,
                float* __restrict__ thermal_out, float* __restrict__ tn_out, int has_prev)
{
  __shared__ float th[2048];
  __shared__ float inv[2048];
  const int t = threadIdx.x;
  for (int j = t; j < 2048; j += 256) {
    float lt = colabs[j] * CROSSTALK;
    float pv = has_prev ? prev_thermal[j] : 0.0f;
    th[j] = 0.7f * pv + 0.3f * lt;
    float d = (float)j;
    inv[j] = (j == 0) ? 0.0f : 1.0f / (d * d);
  }
  __syncthreads();
  const int i = blockIdx.x * 256 + t;
  float s = 0.0f;
  #pragma unroll 4
  for (int j = 0; j < 2048; ++j) {
    int d = i - j; d = d < 0 ? -d : d;
    s += th[j] * inv[d];
  }
  tn_out[i] = s * CROSSTALK;
  thermal_out[i] = th[i];
}

// ---------------------------------------------------------------------------
// Final: x2 = (a2 + tn2) with coherence; out[b,:] = x2[b,:] @ Wout^T + bout.
// a2 is fragment-native fp16.
// ---------------------------------------------------------------------------
__global__ __launch_bounds__(256)
void final_out(const _Float16* __restrict__ a2n, const float* __restrict__ tn2,
               const float* __restrict__ Wout, const float* __restrict__ bout,
               float* __restrict__ out, uint32_t pk0, uint32_t pk1)
{
  const int wave = threadIdx.x >> 6;
  const int lane = threadIdx.x & 63;
  const int b = blockIdx.x * 4 + wave;
  float acc0 = 0.0f, acc1 = 0.0f;
  #pragma unroll
  for (int i = 0; i < 8; ++i) {
    int h = lane * 4 + i * 256;
    half4 v4 = *(const half4*)&a2n[cnat_idx(b, h)];
    float4 tv = *(const float4*)&tn2[h];
    float4 w0 = *(const float4*)&Wout[h];
    float4 w1 = *(const float4*)&Wout[2048 + h];
    float xs[4]  = {(float)v4[0] + tv.x, (float)v4[1] + tv.y,
                    (float)v4[2] + tv.z, (float)v4[3] + tv.w};
    float w0s[4] = {w0.x, w0.y, w0.z, w0.w};
    float w1s[4] = {w1.x, w1.y, w1.z, w1.w};
    uint32_t fb = (uint32_t)(b * 2048 + h);
    #pragma unroll
    for (int e = 0; e < 4; ++e) {
      float ph = COHERENCE * jax_normal(pk0, pk1, fb + e);
      float cp = cos_small(ph);
      float xv = xs[e] + (xs[e] * cp - xs[e]) * COHERENCE;
      acc0 = fmaf(xv, w0s[e], acc0);
      acc1 = fmaf(xv, w1s[e], acc1);
    }
  }
  #pragma unroll
  for (int off = 32; off > 0; off >>= 1) {
    acc0 += __shfl_down(acc0, off);
    acc1 += __shfl_down(acc1, off);
  }
  if (lane == 0) {
    out[(size_t)b * 2 + 0] = acc0 + bout[0];
    out[(size_t)b * 2 + 1] = acc1 + bout[1];
  }
}

extern "C" void kernel_launch(void* const* d_in, const int* in_sizes, int n_in,
                              void* d_out, int out_size, void* d_ws, size_t ws_size,
                              hipStream_t stream)
{
  (void)in_sizes; (void)n_in; (void)out_size; (void)ws_size;
  const float* x    = (const float*)d_in[0];
  const float* W1   = (const float*)d_in[1];
  const float* b1   = (const float*)d_in[2];
  const float* W2   = (const float*)d_in[3];
  const float* b2   = (const float*)d_in[4];
  const float* Wout = (const float*)d_in[5];
  const float* bout = (const float*)d_in[6];
  float* out = (float*)d_out;

  const int M = 8192, H = 2048, Din = 1024;
  const size_t MB = (size_t)1024 * 1024;

  char* ws = (char*)d_ws;
  // [0,32MB): fragment-native fp16 GEMM out (a1, later a2)
  _Float16* a_nat = (_Float16*)ws;
  // [32,64MB): packed fp16 A operand (xpk 16MB for G1; then Apk2 32MB for G2)
  _Float16* Apk = (_Float16*)(ws + 32 * MB);
  // [64,68MB): W1 packed; [68,76MB): W2 packed
  _Float16* W1p = (_Float16*)(ws + 64 * MB);
  _Float16* W2p = (_Float16*)(ws + 68 * MB);
  // [80MB,...): small arrays
  float* small = (float*)(ws + 80 * MB);
  float* colabs1  = small + 0 * H;
  float* colabs2  = small + 1 * H;
  float* thermal1 = small + 2 * H;
  float* thermal2 = small + 3 * H;
  float* tn1      = small + 4 * H;
  float* tn2      = small + 5 * H;
  float* foldb    = small + 6 * H;

  // fold_in keys: key(42) = (0,42); fold_in(key, d) = threefry(key, [0,d])
  uint32_t kn0a, kn0b, kp0a, kp0b, kn1a, kn1b, kp1a, kp1b;
  threefry2x32(0u, 42u, 0u, 0u, kn0a, kn0b);   // noise, layer 0
  threefry2x32(0u, 42u, 0u, 1u, kp0a, kp0b);   // phase, layer 0
  threefry2x32(0u, 42u, 0u, 2u, kn1a, kn1b);   // noise, layer 1
  threefry2x32(0u, 42u, 0u, 3u, kp1a, kp1b);   // phase, layer 1

  hipMemsetAsync(colabs1, 0, 2 * H * sizeof(float), stream);

  // packs (kshift = log2(K/64))
  pack_plane<<<1024, 256, 0, stream>>>(W1, W1p, H, Din, 4, 0);
  pack_plane<<<2048, 256, 0, stream>>>(W2, W2p, H, H, 5, 0);
  pack_plane<<<2048, 256, 0, stream>>>(x, Apk, M, Din, 4, 1);

  const int nblk = (M / BM) * (H / BN);   // 64*16 = 1024 (multiple of 8)
  gemm_f16<<<nblk, 256, 0, stream>>>(Apk, W1p, b1, a_nat, colabs1,
                                     M, H, Din, kn0a, kn0b);
  thermal_tn<<<H / 256, 256, 0, stream>>>(colabs1, nullptr, thermal1, tn1, 0);
  bias_fold<<<H / 4, 256, 0, stream>>>(tn1, W2, b2, foldb, H);
  coherence_pack_small<<<2048, 256, 0, stream>>>(a_nat, tn1, Apk,
                                                 kp0a, kp0b, M, H, 5);
  gemm_f16<<<nblk, 256, 0, stream>>>(Apk, W2p, foldb, a_nat, colabs2,
                                     M, H, H, kn1a, kn1b);
  thermal_tn<<<H / 256, 256, 0, stream>>>(colabs2, thermal1, thermal2, tn2, 1);
  final_out<<<M / 4, 256, 0, stream>>>(a_nat, tn2, Wout, bout, out, kp1a, kp1b);
}